// Round 1
// baseline (2796.633 us; speedup 1.0000x reference)
//
#include <hip/hip_runtime.h>
#include <hip/hip_bf16.h>
#include <float.h>

#define K_NN 20
#define EPS 1e-5f
#define SLOPE 0.2f
constexpr int Bsz = 8;
constexpr int Npts = 2048;
constexpr int NQ = 8;            // knn column-quadrant split
constexpr int BN = Bsz * Npts;   // 16384

// ---------------------------------------------------------------- sq of rows
template<int C>
__global__ __launch_bounds__(256) void sq_kernel(const float* __restrict__ xt,
                                                 float* __restrict__ sq) {
  int p = blockIdx.x * 256 + threadIdx.x;
  if (p >= BN) return;
  const float* r = xt + (size_t)p * C;
  float s = 0.f;
  #pragma unroll 4
  for (int c = 0; c < C; ++c) { float v = r[c]; s += v * v; }
  sq[p] = s;
}

// ------------------------------------------------- knn partial top-k per quadrant
template<int C, int MT>
__global__ __launch_bounds__(64) void knn_part(const float* __restrict__ xt,
    const float* __restrict__ sq, float* __restrict__ pval, int* __restrict__ pidx) {
  constexpr int MQ = Npts / NQ;
  __shared__ __align__(16) float ctrT[C][64];
  __shared__ __align__(16) float chk[MT][C];
  __shared__ float csq[MT];
  const int t = threadIdx.x;
  const int rowblk = blockIdx.x / NQ;
  const int q = blockIdx.x % NQ;
  const int p0 = rowblk * 64;
  const int b = p0 / Npts;

  const float* src = xt + (size_t)p0 * C;
  for (int e = t; e < 64 * C; e += 64) ctrT[e % C][e / C] = src[e];
  __syncthreads();
  float cr[C];
  #pragma unroll
  for (int c = 0; c < C; ++c) cr[c] = ctrT[c][t];
  const float sqn = sq[p0 + t];

  float vals[K_NN]; int ids[K_NN];
  #pragma unroll
  for (int i = 0; i < K_NN; ++i) { vals[i] = -FLT_MAX; ids[i] = 0; }

  const int mbase = q * MQ;
  for (int m0 = mbase; m0 < mbase + MQ; m0 += MT) {
    __syncthreads();
    const float* s2 = xt + ((size_t)b * Npts + m0) * C;
    for (int e = t; e < MT * C; e += 64) chk[e / C][e % C] = s2[e];
    for (int e = t; e < MT; e += 64) csq[e] = sq[b * Npts + m0 + e];
    __syncthreads();
    for (int j = 0; j < MT; ++j) {
      float dot = 0.f;
      if constexpr (C % 4 == 0) {
        const float4* cp = (const float4*)(&chk[j][0]);
        #pragma unroll
        for (int c4 = 0; c4 < C / 4; ++c4) {
          float4 v = cp[c4];
          dot += cr[c4*4+0]*v.x + cr[c4*4+1]*v.y + cr[c4*4+2]*v.z + cr[c4*4+3]*v.w;
        }
      } else {
        #pragma unroll
        for (int c = 0; c < C; ++c) dot += cr[c] * chk[j][c];
      }
      float nd = 2.0f * dot - sqn - csq[j];
      if (nd > vals[K_NN - 1]) {          // strict: ties keep earlier (lower) index
        vals[K_NN - 1] = nd; ids[K_NN - 1] = m0 + j;
        #pragma unroll
        for (int i = K_NN - 1; i >= 1; --i) {
          if (vals[i] > vals[i - 1]) {    // strict: stable insertion
            float tv = vals[i]; vals[i] = vals[i-1]; vals[i-1] = tv;
            int ti = ids[i]; ids[i] = ids[i-1]; ids[i-1] = ti;
          }
        }
      }
    }
  }
  size_t base = ((size_t)q * BN + (p0 + t)) * K_NN;
  #pragma unroll
  for (int i = 0; i < K_NN; ++i) { pval[base + i] = vals[i]; pidx[base + i] = ids[i]; }
}

// ------------------------------------------------- merge NQ sorted lists -> top-20
__global__ __launch_bounds__(256) void knn_merge(const float* __restrict__ pval,
    const int* __restrict__ pidx, int* __restrict__ idxout) {
  int p = blockIdx.x * 256 + threadIdx.x;
  if (p >= BN) return;
  float vals[K_NN]; int ids[K_NN];
  size_t base = (size_t)p * K_NN;
  #pragma unroll
  for (int i = 0; i < K_NN; ++i) { vals[i] = pval[base + i]; ids[i] = pidx[base + i]; }
  for (int q = 1; q < NQ; ++q) {
    size_t b2 = ((size_t)q * BN + p) * K_NN;
    #pragma unroll
    for (int i = 0; i < K_NN; ++i) {
      float v = pval[b2 + i];
      if (v <= vals[K_NN - 1]) break;     // sorted source list -> rest also fail
      int m = pidx[b2 + i];
      vals[K_NN - 1] = v; ids[K_NN - 1] = m;
      #pragma unroll
      for (int r = K_NN - 1; r >= 1; --r) {
        if (vals[r] > vals[r - 1]) {
          float tv = vals[r]; vals[r] = vals[r-1]; vals[r-1] = tv;
          int ti = ids[r]; ids[r] = ids[r-1]; ids[r-1] = ti;
        }
      }
    }
  }
  int* op = idxout + (size_t)p * K_NN;
  #pragma unroll
  for (int i = 0; i < K_NN; ++i) op[i] = ids[i];
}

// ------------------------------------------------- edge conv: raw max/min + stats
template<int C, int O, int G>
__global__ __launch_bounds__(O) void edge_kernel(const float* __restrict__ xt,
    const int* __restrict__ idx, const float* __restrict__ W,
    float* __restrict__ mx, float* __restrict__ mn,
    float* __restrict__ psum, float* __restrict__ psq) {
  __shared__ __align__(16) float pts[G][K_NN + 1][C];
  __shared__ int ids[G][K_NN + 1];
  const int t = threadIdx.x;
  const int p0 = blockIdx.x * G;
  const int b = p0 / Npts;

  for (int e = t; e < G * (K_NN + 1); e += O) {
    int g = e / (K_NN + 1), j = e % (K_NN + 1);
    int p = p0 + g;
    ids[g][j] = (j == 0) ? p : (b * Npts + idx[(size_t)p * K_NN + (j - 1)]);
  }
  __syncthreads();
  for (int e = t; e < G * (K_NN + 1) * C; e += O) {
    int g = e / ((K_NN + 1) * C), rem = e % ((K_NN + 1) * C);
    int j = rem / C, c = rem % C;
    pts[g][j][c] = xt[(size_t)ids[g][j] * C + c];
  }
  __syncthreads();

  const float* Wr = W + (size_t)t * (2 * C);
  float lsum = 0.f, lsq = 0.f;
  for (int g = 0; g < G; ++g) {
    float yk[K_NN];
    #pragma unroll
    for (int k = 0; k < K_NN; ++k) yk[k] = 0.f;
    float u = 0.f, v2 = 0.f;
    if constexpr (C % 4 == 0) {
      for (int c4 = 0; c4 < C / 4; ++c4) {
        float4 wlo = *(const float4*)(Wr + c4 * 4);
        float4 whi = *(const float4*)(Wr + C + c4 * 4);
        float4 cc  = *(const float4*)(&pts[g][0][c4 * 4]);
        u  += wlo.x*cc.x + wlo.y*cc.y + wlo.z*cc.z + wlo.w*cc.w;
        v2 += whi.x*cc.x + whi.y*cc.y + whi.z*cc.z + whi.w*cc.w;
        #pragma unroll
        for (int k = 0; k < K_NN; ++k) {
          float4 pk = *(const float4*)(&pts[g][k + 1][c4 * 4]);
          yk[k] += wlo.x*pk.x + wlo.y*pk.y + wlo.z*pk.z + wlo.w*pk.w;
        }
      }
    } else {
      for (int c = 0; c < C; ++c) {
        float wl = Wr[c], wh = Wr[C + c], cc = pts[g][0][c];
        u += wl * cc; v2 += wh * cc;
        #pragma unroll
        for (int k = 0; k < K_NN; ++k) yk[k] += wl * pts[g][k + 1][c];
      }
    }
    float base = v2 - u;   // y_k = W_lo·nb_k + (W_hi - W_lo)·ctr
    float vmax = -FLT_MAX, vmin = FLT_MAX;
    #pragma unroll
    for (int k = 0; k < K_NN; ++k) {
      float y = yk[k] + base;
      lsum += y; lsq += y * y;
      vmax = fmaxf(vmax, y); vmin = fminf(vmin, y);
    }
    int n = (p0 + g) % Npts;
    mx[((size_t)b * O + t) * Npts + n] = vmax;
    mn[((size_t)b * O + t) * Npts + n] = vmin;
  }
  psum[(size_t)blockIdx.x * O + t] = lsum;
  psq [(size_t)blockIdx.x * O + t] = lsq;
}

// ------------------------------------------------- finalize BN stats per channel
__global__ __launch_bounds__(256) void stats_kernel(const float* __restrict__ psum,
    const float* __restrict__ psq, int nblk, int O,
    const float* __restrict__ gamma, const float* __restrict__ beta,
    float* __restrict__ scale, float* __restrict__ bias) {
  const int o = blockIdx.x;
  const int t = threadIdx.x;
  double s = 0.0, ss = 0.0;
  for (int i = t; i < nblk; i += 256) {
    s  += (double)psum[(size_t)i * O + o];
    ss += (double)psq [(size_t)i * O + o];
  }
  __shared__ double sh[256], sh2[256];
  sh[t] = s; sh2[t] = ss;
  __syncthreads();
  for (int w = 128; w > 0; w >>= 1) {
    if (t < w) { sh[t] += sh[t + w]; sh2[t] += sh2[t + w]; }
    __syncthreads();
  }
  if (t == 0) {
    double cnt = (double)Bsz * Npts * K_NN;
    double m = sh[0] / cnt;
    double var = sh2[0] / cnt - m * m;
    float g = gamma[o];
    float sc = g * rsqrtf((float)var + EPS);
    scale[o] = sc;
    bias[o] = beta[o] - (float)m * sc;
  }
}

// ------------------------------------------------- normalize + lrelu, both layouts
template<int O, bool NC>
__global__ __launch_bounds__(256) void apply_kernel(const float* __restrict__ mx,
    const float* __restrict__ mn, const float* __restrict__ scale,
    const float* __restrict__ bias, float* __restrict__ xcn, float* __restrict__ xnc) {
  int i = blockIdx.x * 256 + threadIdx.x;
  if (i >= BN * O) return;
  int n = i % Npts;
  int o = (i / Npts) % O;
  int b = i / (Npts * O);
  float sc = scale[o];
  float raw = (sc >= 0.f) ? mx[i] : mn[i];   // monotonic trick: max for +scale, min for -scale
  float y = raw * sc + bias[o];
  y = (y >= 0.f) ? y : SLOPE * y;
  xcn[i] = y;
  if constexpr (NC) xnc[((size_t)b * Npts + n) * O + o] = y;
}

// ------------------------------------------------- concat + global max-pool over N
__global__ __launch_bounds__(64) void pool_kernel(const float* __restrict__ x1,
    const float* __restrict__ x2, const float* __restrict__ x3,
    float* __restrict__ pooled) {
  int bc = blockIdx.x;
  int b = bc / 448, c = bc % 448;
  const float* row;
  if (c < 64)       row = x1 + ((size_t)b * 64  + c)        * Npts;
  else if (c < 192) row = x2 + ((size_t)b * 128 + (c - 64)) * Npts;
  else              row = x3 + ((size_t)b * 256 + (c - 192))* Npts;
  float m = -FLT_MAX;
  for (int n = threadIdx.x; n < Npts; n += 64) m = fmaxf(m, row[n]);
  #pragma unroll
  for (int w = 32; w > 0; w >>= 1) m = fmaxf(m, __shfl_down(m, w));
  if (threadIdx.x == 0) pooled[bc] = m;
}

// ------------------------------------------------- FC layers
template<int CIN, bool LRELU>
__global__ __launch_bounds__(64) void fc_kernel(const float* __restrict__ in,
    const float* __restrict__ Wt, float* __restrict__ out, int JO) {
  int j = blockIdx.x;
  const float* wr = Wt + (size_t)j * CIN;
  float acc[Bsz];
  #pragma unroll
  for (int b = 0; b < Bsz; ++b) acc[b] = 0.f;
  for (int c = threadIdx.x; c < CIN; c += 64) {
    float w = wr[c];
    #pragma unroll
    for (int b = 0; b < Bsz; ++b) acc[b] += in[b * CIN + c] * w;
  }
  #pragma unroll
  for (int b = 0; b < Bsz; ++b) {
    float v = acc[b];
    #pragma unroll
    for (int w = 32; w > 0; w >>= 1) v += __shfl_down(v, w);
    if (threadIdx.x == 0) {
      if (LRELU) v = (v >= 0.f) ? v : SLOPE * v;
      out[b * JO + j] = v;
    }
  }
}

// ================================================================ launch
extern "C" void kernel_launch(void* const* d_in, const int* in_sizes, int n_in,
                              void* d_out, int out_size, void* d_ws, size_t ws_size,
                              hipStream_t stream) {
  const float* x   = (const float*)d_in[0];
  const float* W1  = (const float*)d_in[1];
  const float* g1  = (const float*)d_in[2];
  const float* b1  = (const float*)d_in[3];
  const float* W2  = (const float*)d_in[4];
  const float* g2  = (const float*)d_in[5];
  const float* b2  = (const float*)d_in[6];
  const float* W3  = (const float*)d_in[7];
  const float* g3  = (const float*)d_in[8];
  const float* b3  = (const float*)d_in[9];
  const float* L1  = (const float*)d_in[10];
  const float* L2  = (const float*)d_in[11];
  float* out = (float*)d_out;

  float* ws = (float*)d_ws;
  size_t off = 0;
  float* sq    = ws + off; off += BN;
  int*   idxb  = (int*)(ws + off); off += (size_t)BN * K_NN;
  float* mx    = ws + off; off += (size_t)Bsz * 256 * Npts;
  float* mn    = ws + off; off += (size_t)Bsz * 256 * Npts;
  float* psum  = ws + off; off += (size_t)4096 * 256;
  float* psq   = ws + off; off += (size_t)4096 * 256;
  float* scale = ws + off; off += 256;
  float* bias  = ws + off; off += 256;
  float* x1nc  = ws + off; off += (size_t)BN * 64;
  float* x1cn  = ws + off; off += (size_t)BN * 64;
  float* x2nc  = ws + off; off += (size_t)BN * 128;
  float* x2cn  = ws + off; off += (size_t)BN * 128;
  float* x3cn  = ws + off; off += (size_t)BN * 256;
  float* pooled= ws + off; off += Bsz * 448;
  float* h     = ws + off; off += Bsz * 1024;
  // knn partial lists overlay the mx/mn buffers (disjoint lifetimes)
  float* pval = mx;
  int*   pidx = (int*)mn;

  // ---- edge block 1: C=3 -> O=64 (input x is already (B,N,3) point-major)
  sq_kernel<3><<<64, 256, 0, stream>>>(x, sq);
  knn_part<3, 64><<<(BN / 64) * NQ, 64, 0, stream>>>(x, sq, pval, pidx);
  knn_merge<<<64, 256, 0, stream>>>(pval, pidx, idxb);
  edge_kernel<3, 64, 8><<<BN / 8, 64, 0, stream>>>(x, idxb, W1, mx, mn, psum, psq);
  stats_kernel<<<64, 256, 0, stream>>>(psum, psq, BN / 8, 64, g1, b1, scale, bias);
  apply_kernel<64, true><<<BN * 64 / 256, 256, 0, stream>>>(mx, mn, scale, bias, x1cn, x1nc);

  // ---- edge block 2: C=64 -> O=128
  sq_kernel<64><<<64, 256, 0, stream>>>(x1nc, sq);
  knn_part<64, 64><<<(BN / 64) * NQ, 64, 0, stream>>>(x1nc, sq, pval, pidx);
  knn_merge<<<64, 256, 0, stream>>>(pval, pidx, idxb);
  edge_kernel<64, 128, 8><<<BN / 8, 128, 0, stream>>>(x1nc, idxb, W2, mx, mn, psum, psq);
  stats_kernel<<<128, 256, 0, stream>>>(psum, psq, BN / 8, 128, g2, b2, scale, bias);
  apply_kernel<128, true><<<BN * 128 / 256, 256, 0, stream>>>(mx, mn, scale, bias, x2cn, x2nc);

  // ---- edge block 3: C=128 -> O=256
  sq_kernel<128><<<64, 256, 0, stream>>>(x2nc, sq);
  knn_part<128, 32><<<(BN / 64) * NQ, 64, 0, stream>>>(x2nc, sq, pval, pidx);
  knn_merge<<<64, 256, 0, stream>>>(pval, pidx, idxb);
  edge_kernel<128, 256, 4><<<BN / 4, 256, 0, stream>>>(x2nc, idxb, W3, mx, mn, psum, psq);
  stats_kernel<<<256, 256, 0, stream>>>(psum, psq, BN / 4, 256, g3, b3, scale, bias);
  apply_kernel<256, false><<<BN * 256 / 256, 256, 0, stream>>>(mx, mn, scale, bias, x3cn, nullptr);

  // ---- head
  pool_kernel<<<Bsz * 448, 64, 0, stream>>>(x1cn, x2cn, x3cn, pooled);
  fc_kernel<448, true><<<1024, 64, 0, stream>>>(pooled, L1, h, 1024);
  fc_kernel<1024, false><<<2500, 64, 0, stream>>>(h, L2, out, 2500);
}

// Round 2
// 2443.157 us; speedup vs baseline: 1.1447x; 1.1447x over previous
//
#include <hip/hip_runtime.h>
#include <hip/hip_bf16.h>
#include <float.h>

#define K_NN 20
#define EPS 1e-5f
#define SLOPE 0.2f
constexpr int Bsz = 8;
constexpr int Npts = 2048;
constexpr int NQ = 8;            // knn candidate-quadrant split
constexpr int BN = Bsz * Npts;   // 16384

__device__ __forceinline__ float dot4(float4 a, float4 b) {
  return a.x*b.x + a.y*b.y + a.z*b.z + a.w*b.w;
}
// order-preserving float<->uint encoding for atomicMax pooling (exact, deterministic)
__device__ __forceinline__ unsigned encf(float f) {
  unsigned u = __float_as_uint(f);
  return (u & 0x80000000u) ? ~u : (u | 0x80000000u);
}
__device__ __forceinline__ float decf(unsigned e) {
  unsigned u = (e & 0x80000000u) ? (e & 0x7fffffffu) : ~e;
  return __uint_as_float(u);
}

// ---------------------------------------------------------------- sq of rows
template<int C>
__global__ __launch_bounds__(256) void sq_kernel(const float* __restrict__ xt,
                                                 float* __restrict__ sq) {
  int p = blockIdx.x * 256 + threadIdx.x;
  if (p >= BN) return;
  const float* r = xt + (size_t)p * C;
  float s = 0.f;
  if constexpr (C % 4 == 0) {
    for (int c4 = 0; c4 < C / 4; ++c4) { float4 v = *(const float4*)(r + c4 * 4); s += dot4(v, v); }
  } else {
    #pragma unroll
    for (int c = 0; c < C; ++c) { float v = r[c]; s += v * v; }
  }
  sq[p] = s;
}

// ------------------------------------------------- knn partial top-k per quadrant
// 256-thread blocks: 4 waves x 64 rows each, shared candidate staging.
template<int C, int MT>
__global__ __launch_bounds__(256) void knn_part(const float* __restrict__ xt,
    const float* __restrict__ sq, float* __restrict__ pval, int* __restrict__ pidx) {
  constexpr int MQ = Npts / NQ;
  __shared__ __align__(16) float chk[MT][C];
  __shared__ float csq[MT];
  const int t = threadIdx.x, w = t >> 6, l = t & 63;
  const int rowblk = blockIdx.x / NQ;
  const int q = blockIdx.x - rowblk * NQ;
  const int p0 = rowblk * 256;
  const int b = p0 / Npts;
  const int myrow = p0 + w * 64 + l;

  float cr[C];
  if constexpr (C >= 16) {
    __shared__ __align__(16) float stg[64][C + 4];
    for (int wv = 0; wv < 4; ++wv) {
      for (int e = t; e < 64 * C; e += 256) stg[e / C][e - (e / C) * C] =
          xt[((size_t)(p0 + wv * 64)) * C + e];
      __syncthreads();
      if (w == wv) {
        #pragma unroll
        for (int c4 = 0; c4 < C / 4; ++c4)
          *(float4*)(cr + c4 * 4) = *(const float4*)(&stg[l][c4 * 4]);
      }
      __syncthreads();
    }
  } else {
    #pragma unroll
    for (int c = 0; c < C; ++c) cr[c] = xt[(size_t)myrow * C + c];
  }
  const float sqn = sq[myrow];

  float vals[K_NN]; int ids[K_NN];
  #pragma unroll
  for (int i = 0; i < K_NN; ++i) { vals[i] = -FLT_MAX; ids[i] = 0; }

  const int mbase = q * MQ;
  for (int m0 = mbase; m0 < mbase + MQ; m0 += MT) {
    __syncthreads();
    const float* s2 = xt + ((size_t)b * Npts + m0) * C;
    for (int e = t; e < MT * C; e += 256) chk[e / C][e - (e / C) * C] = s2[e];
    for (int e = t; e < MT; e += 256) csq[e] = sq[b * Npts + m0 + e];
    __syncthreads();
    for (int j = 0; j < MT; ++j) {
      float dt = 0.f;
      if constexpr (C % 4 == 0) {
        #pragma unroll
        for (int c4 = 0; c4 < C / 4; ++c4)
          dt += dot4(*(const float4*)(cr + c4 * 4), *(const float4*)(&chk[j][c4 * 4]));
      } else {
        #pragma unroll
        for (int c = 0; c < C; ++c) dt += cr[c] * chk[j][c];
      }
      float nd = 2.f * dt - sqn - csq[j];
      if (nd > vals[K_NN - 1]) {          // strict: ties keep earlier (lower) index
        vals[K_NN - 1] = nd; ids[K_NN - 1] = m0 + j;
        #pragma unroll
        for (int i = K_NN - 1; i >= 1; --i) {
          if (vals[i] > vals[i - 1]) {
            float tv = vals[i]; vals[i] = vals[i-1]; vals[i-1] = tv;
            int ti = ids[i]; ids[i] = ids[i-1]; ids[i-1] = ti;
          }
        }
      }
    }
  }
  size_t base = ((size_t)q * BN + myrow) * K_NN;
  #pragma unroll
  for (int i = 0; i < K_NN; ++i) { pval[base + i] = vals[i]; pidx[base + i] = ids[i]; }
}

// ------------------------------------------------- merge NQ sorted lists -> top-20
__global__ __launch_bounds__(256) void knn_merge(const float* __restrict__ pval,
    const int* __restrict__ pidx, int* __restrict__ idxout) {
  int p = blockIdx.x * 256 + threadIdx.x;
  if (p >= BN) return;
  float vals[K_NN]; int ids[K_NN];
  size_t base = (size_t)p * K_NN;
  #pragma unroll
  for (int i = 0; i < K_NN; ++i) { vals[i] = pval[base + i]; ids[i] = pidx[base + i]; }
  for (int q = 1; q < NQ; ++q) {
    size_t b2 = ((size_t)q * BN + p) * K_NN;
    #pragma unroll
    for (int i = 0; i < K_NN; ++i) {
      float v = pval[b2 + i];
      if (v <= vals[K_NN - 1]) break;
      int m = pidx[b2 + i];
      vals[K_NN - 1] = v; ids[K_NN - 1] = m;
      #pragma unroll
      for (int r = K_NN - 1; r >= 1; --r) {
        if (vals[r] > vals[r - 1]) {
          float tv = vals[r]; vals[r] = vals[r-1]; vals[r-1] = tv;
          int ti = ids[r]; ids[r] = ids[r-1]; ids[r-1] = ti;
        }
      }
    }
  }
  int* op = idxout + (size_t)p * K_NN;
  #pragma unroll
  for (int i = 0; i < K_NN; ++i) op[i] = ids[i];
}

// ------------------------------------------------- edge conv: raw max/min + stats
// CPT channels per thread; WP waves per point-group; NPG groups per block.
// Writes mx/mn in NC layout [b][n][o] -> coalesced 256B stores.
template<int C, int O, int G, int NPG, int CPT>
__global__ __launch_bounds__(256) void edge_kernel(const float* __restrict__ xt,
    const int* __restrict__ idx, const float* __restrict__ W,
    float* __restrict__ mx, float* __restrict__ mn,
    float* __restrict__ psum, float* __restrict__ psq) {
  constexpr int WP = O / (64 * CPT);
  constexpr int TPB = 64 * WP * NPG;
  constexpr int PPG = G / NPG;
  static_assert(TPB == 256, "block must be 256 threads");
  __shared__ __align__(16) float pts[G][K_NN + 1][C];
  __shared__ int ids[G][K_NN + 1];
  __shared__ float shps[NPG][O];
  __shared__ float shpq[NPG][O];
  const int t = threadIdx.x;
  const int p0 = blockIdx.x * G;
  const int b = p0 / Npts;

  for (int e = t; e < G * (K_NN + 1); e += TPB) {
    int g = e / (K_NN + 1), j = e - g * (K_NN + 1);
    ids[g][j] = (j == 0) ? (p0 + g) : (b * Npts + idx[(size_t)(p0 + g) * K_NN + (j - 1)]);
  }
  __syncthreads();
  for (int e = t; e < G * (K_NN + 1) * C; e += TPB) {
    int g = e / ((K_NN + 1) * C), rem = e - g * ((K_NN + 1) * C);
    int j = rem / C, c = rem - j * C;
    pts[g][j][c] = xt[(size_t)ids[g][j] * C + c];
  }
  __syncthreads();

  const int w = t >> 6, l = t & 63;
  const int pg = w / WP, wp = w - pg * WP;
  const int o0 = wp * 64 + l;
  float ls0 = 0.f, lq0 = 0.f, ls1 = 0.f, lq1 = 0.f;

  for (int it = 0; it < PPG; ++it) {
    const int g = pg * PPG + it;
    float yk0[K_NN], yk1[K_NN];
    float u0 = 0.f, v0 = 0.f, u1 = 0.f, v1 = 0.f;
    #pragma unroll
    for (int k = 0; k < K_NN; ++k) { yk0[k] = 0.f; yk1[k] = 0.f; }
    const float* W0 = W + (size_t)o0 * (2 * C);
    const float* W1 = W + (size_t)(o0 + O / 2) * (2 * C);
    if constexpr (C % 4 == 0) {
      for (int c4 = 0; c4 < C / 4; ++c4) {
        const float4 wl0 = *(const float4*)(W0 + c4 * 4);
        const float4 wh0 = *(const float4*)(W0 + C + c4 * 4);
        float4 wl1, wh1;
        if constexpr (CPT == 2) {
          wl1 = *(const float4*)(W1 + c4 * 4);
          wh1 = *(const float4*)(W1 + C + c4 * 4);
        }
        const float4 cc = *(const float4*)(&pts[g][0][c4 * 4]);
        u0 += dot4(wl0, cc); v0 += dot4(wh0, cc);
        if constexpr (CPT == 2) { u1 += dot4(wl1, cc); v1 += dot4(wh1, cc); }
        #pragma unroll
        for (int k = 0; k < K_NN; ++k) {
          const float4 pk = *(const float4*)(&pts[g][k + 1][c4 * 4]);
          yk0[k] += dot4(wl0, pk);
          if constexpr (CPT == 2) yk1[k] += dot4(wl1, pk);
        }
      }
    } else {
      #pragma unroll
      for (int c = 0; c < C; ++c) {
        const float wl = W0[c], wh = W0[C + c], ccv = pts[g][0][c];
        u0 += wl * ccv; v0 += wh * ccv;
        #pragma unroll
        for (int k = 0; k < K_NN; ++k) yk0[k] += wl * pts[g][k + 1][c];
      }
    }
    const int n = p0 + g - b * Npts;
    const size_t obase = ((size_t)b * Npts + n) * O;
    {
      const float base = v0 - u0;   // y_k = W_lo*nb_k + (W_hi - W_lo)*ctr
      float vmx = -FLT_MAX, vmn = FLT_MAX;
      #pragma unroll
      for (int k = 0; k < K_NN; ++k) {
        float y = yk0[k] + base;
        ls0 += y; lq0 += y * y;
        vmx = fmaxf(vmx, y); vmn = fminf(vmn, y);
      }
      mx[obase + o0] = vmx; mn[obase + o0] = vmn;
    }
    if constexpr (CPT == 2) {
      const float base = v1 - u1;
      float vmx = -FLT_MAX, vmn = FLT_MAX;
      #pragma unroll
      for (int k = 0; k < K_NN; ++k) {
        float y = yk1[k] + base;
        ls1 += y; lq1 += y * y;
        vmx = fmaxf(vmx, y); vmn = fminf(vmn, y);
      }
      mx[obase + o0 + O / 2] = vmx; mn[obase + o0 + O / 2] = vmn;
    }
  }

  shps[pg][o0] = ls0; shpq[pg][o0] = lq0;
  if constexpr (CPT == 2) { shps[pg][o0 + O / 2] = ls1; shpq[pg][o0 + O / 2] = lq1; }
  __syncthreads();
  if (t < O) {
    float s = 0.f, qq = 0.f;
    #pragma unroll
    for (int i = 0; i < NPG; ++i) { s += shps[i][t]; qq += shpq[i][t]; }
    psum[(size_t)blockIdx.x * O + t] = s;
    psq [(size_t)blockIdx.x * O + t] = qq;
  }
}

// ------------------------------------------------- finalize BN stats per channel
template<int O>
__global__ __launch_bounds__(256) void stats_kernel(const float* __restrict__ psum,
    const float* __restrict__ psq, int nblk,
    const float* __restrict__ gamma, const float* __restrict__ beta,
    float* __restrict__ scale, float* __restrict__ bias) {
  const int l = threadIdx.x & 63, w = threadIdx.x >> 6;
  const int o = blockIdx.x * 64 + l;
  double s = 0.0, ss = 0.0;
  for (int i = w; i < nblk; i += 4) {
    s  += (double)psum[(size_t)i * O + o];
    ss += (double)psq [(size_t)i * O + o];
  }
  __shared__ double sh[2][4][64];
  sh[0][w][l] = s; sh[1][w][l] = ss;
  __syncthreads();
  if (w == 0) {
    s  = sh[0][0][l] + sh[0][1][l] + sh[0][2][l] + sh[0][3][l];
    ss = sh[1][0][l] + sh[1][1][l] + sh[1][2][l] + sh[1][3][l];
    double cnt = (double)Bsz * Npts * K_NN;
    double m = s / cnt;
    double var = ss / cnt - m * m;
    float g = gamma[o];
    float sc = g * rsqrtf((float)var + EPS);
    scale[o] = sc;
    bias[o] = beta[o] - (float)m * sc;
  }
}

// ------------------------------------------------- reset pooled accumulators
__global__ __launch_bounds__(256) void reset_pool(unsigned* __restrict__ pooled) {
  int i = blockIdx.x * 256 + threadIdx.x;
  if (i < Bsz * 448) pooled[i] = 0u;   // 0 < encf(f) for all finite f
}

// ------------------------------------------------- normalize + lrelu + fused max-pool
// reads/writes NC layout; one atomicMax per (block, channel)
template<int O, int COFF, bool WNC>
__global__ __launch_bounds__(256) void apply_kernel(const float* __restrict__ mx,
    const float* __restrict__ mn, const float* __restrict__ scale,
    const float* __restrict__ bias, float* __restrict__ xnc,
    unsigned* __restrict__ pooled) {
  constexpr int OT = O / 64;
  constexpr int NCH = Npts / 256;
  const int bid = blockIdx.x;
  const int nchunk = bid % NCH;
  const int ot = (bid / NCH) % OT;
  const int b = bid / (NCH * OT);
  const int l = threadIdx.x & 63, w = threadIdx.x >> 6;
  const int o = ot * 64 + l;
  const float sc = scale[o], bs = bias[o];
  const bool pos = (sc >= 0.f);
  float vmax = -FLT_MAX;
  const int n0 = nchunk * 256;
  for (int i = 0; i < 64; ++i) {
    int n = n0 + w + i * 4;
    size_t ix = ((size_t)b * Npts + n) * O + o;
    float raw = pos ? mx[ix] : mn[ix];   // max for +scale, min for -scale
    float y = raw * sc + bs;
    y = (y >= 0.f) ? y : SLOPE * y;
    if constexpr (WNC) xnc[ix] = y;
    vmax = fmaxf(vmax, y);
  }
  __shared__ float sh[4][64];
  sh[w][l] = vmax;
  __syncthreads();
  if (w == 0) {
    float m = fmaxf(fmaxf(sh[0][l], sh[1][l]), fmaxf(sh[2][l], sh[3][l]));
    atomicMax(pooled + b * 448 + COFF + o, encf(m));
  }
}

// ------------------------------------------------- FC layers
template<int CIN, bool LRELU, bool DECODE>
__global__ __launch_bounds__(64) void fc_kernel(const void* __restrict__ inv,
    const float* __restrict__ Wt, float* __restrict__ out, int JO) {
  int j = blockIdx.x;
  const float* wr = Wt + (size_t)j * CIN;
  float acc[Bsz];
  #pragma unroll
  for (int b = 0; b < Bsz; ++b) acc[b] = 0.f;
  for (int c = threadIdx.x; c < CIN; c += 64) {
    float wv = wr[c];
    #pragma unroll
    for (int b = 0; b < Bsz; ++b) {
      float x;
      if constexpr (DECODE) x = decf(((const unsigned*)inv)[b * CIN + c]);
      else                  x = ((const float*)inv)[b * CIN + c];
      acc[b] += x * wv;
    }
  }
  #pragma unroll
  for (int b = 0; b < Bsz; ++b) {
    float v = acc[b];
    #pragma unroll
    for (int w = 32; w > 0; w >>= 1) v += __shfl_down(v, w);
    if (threadIdx.x == 0) {
      if (LRELU) v = (v >= 0.f) ? v : SLOPE * v;
      out[b * JO + j] = v;
    }
  }
}

// ================================================================ launch
extern "C" void kernel_launch(void* const* d_in, const int* in_sizes, int n_in,
                              void* d_out, int out_size, void* d_ws, size_t ws_size,
                              hipStream_t stream) {
  const float* x   = (const float*)d_in[0];
  const float* W1  = (const float*)d_in[1];
  const float* g1  = (const float*)d_in[2];
  const float* b1  = (const float*)d_in[3];
  const float* W2  = (const float*)d_in[4];
  const float* g2  = (const float*)d_in[5];
  const float* b2  = (const float*)d_in[6];
  const float* W3  = (const float*)d_in[7];
  const float* g3  = (const float*)d_in[8];
  const float* b3  = (const float*)d_in[9];
  const float* L1  = (const float*)d_in[10];
  const float* L2  = (const float*)d_in[11];
  float* out = (float*)d_out;

  float* ws = (float*)d_ws;
  size_t off = 0;
  float* sq    = ws + off; off += BN;
  int*   idxb  = (int*)(ws + off); off += (size_t)BN * K_NN;
  float* mx    = ws + off; off += (size_t)BN * 256;
  float* mn    = ws + off; off += (size_t)BN * 256;
  float* psum  = ws + off; off += (size_t)4096 * 256;
  float* psq   = ws + off; off += (size_t)4096 * 256;
  float* scale = ws + off; off += 256;
  float* bias  = ws + off; off += 256;
  float* x1nc  = ws + off; off += (size_t)BN * 64;
  float* x2nc  = ws + off; off += (size_t)BN * 128;
  unsigned* pooled = (unsigned*)(ws + off); off += Bsz * 448;
  float* h     = ws + off; off += Bsz * 1024;
  // knn partial lists overlay mx/mn (disjoint lifetimes)
  float* pval = mx;
  int*   pidx = (int*)mn;

  reset_pool<<<14, 256, 0, stream>>>(pooled);

  // ---- edge block 1: C=3 -> O=64
  sq_kernel<3><<<64, 256, 0, stream>>>(x, sq);
  knn_part<3, 64><<<(BN / 256) * NQ, 256, 0, stream>>>(x, sq, pval, pidx);
  knn_merge<<<64, 256, 0, stream>>>(pval, pidx, idxb);
  edge_kernel<3, 64, 16, 4, 1><<<BN / 16, 256, 0, stream>>>(x, idxb, W1, mx, mn, psum, psq);
  stats_kernel<64><<<1, 256, 0, stream>>>(psum, psq, BN / 16, g1, b1, scale, bias);
  apply_kernel<64, 0, true><<<8 * 1 * 8, 256, 0, stream>>>(mx, mn, scale, bias, x1nc, pooled);

  // ---- edge block 2: C=64 -> O=128
  sq_kernel<64><<<64, 256, 0, stream>>>(x1nc, sq);
  knn_part<64, 64><<<(BN / 256) * NQ, 256, 0, stream>>>(x1nc, sq, pval, pidx);
  knn_merge<<<64, 256, 0, stream>>>(pval, pidx, idxb);
  edge_kernel<64, 128, 8, 4, 2><<<BN / 8, 256, 0, stream>>>(x1nc, idxb, W2, mx, mn, psum, psq);
  stats_kernel<128><<<2, 256, 0, stream>>>(psum, psq, BN / 8, g2, b2, scale, bias);
  apply_kernel<128, 64, true><<<8 * 2 * 8, 256, 0, stream>>>(mx, mn, scale, bias, x2nc, pooled);

  // ---- edge block 3: C=128 -> O=256
  sq_kernel<128><<<64, 256, 0, stream>>>(x2nc, sq);
  knn_part<128, 32><<<(BN / 256) * NQ, 256, 0, stream>>>(x2nc, sq, pval, pidx);
  knn_merge<<<64, 256, 0, stream>>>(pval, pidx, idxb);
  edge_kernel<128, 256, 4, 2, 2><<<BN / 4, 256, 0, stream>>>(x2nc, idxb, W3, mx, mn, psum, psq);
  stats_kernel<256><<<4, 256, 0, stream>>>(psum, psq, BN / 4, g3, b3, scale, bias);
  apply_kernel<256, 192, false><<<8 * 4 * 8, 256, 0, stream>>>(mx, mn, scale, bias, nullptr, pooled);

  // ---- head
  fc_kernel<448, true, true><<<1024, 64, 0, stream>>>(pooled, L1, h, 1024);
  fc_kernel<1024, false, false><<<2500, 64, 0, stream>>>(h, L2, out, 2500);
}

// Round 3
// 1689.955 us; speedup vs baseline: 1.6549x; 1.4457x over previous
//
#include <hip/hip_runtime.h>
#include <hip/hip_bf16.h>
#include <float.h>

#define K_NN 20
#define EPS 1e-5f
#define SLOPE 0.2f
constexpr int Bsz = 8;
constexpr int Npts = 2048;
constexpr int NQ = 8;            // knn candidate-quadrant split
constexpr int BN = Bsz * Npts;   // 16384

typedef __attribute__((ext_vector_type(8))) short short8v;
typedef __attribute__((ext_vector_type(4))) float f32x4;

__device__ __forceinline__ float dot4(float4 a, float4 b) {
  return a.x*b.x + a.y*b.y + a.z*b.z + a.w*b.w;
}
// order-preserving float<->uint encoding for atomicMax pooling (exact, deterministic)
__device__ __forceinline__ unsigned encf(float f) {
  unsigned u = __float_as_uint(f);
  return (u & 0x80000000u) ? ~u : (u | 0x80000000u);
}
__device__ __forceinline__ float decf(unsigned e) {
  unsigned u = (e & 0x80000000u) ? (e & 0x7fffffffu) : ~e;
  return __uint_as_float(u);
}
// bf16 split helpers (RNE)
__device__ __forceinline__ unsigned short f2bf(float x) {
  unsigned u = __float_as_uint(x);
  unsigned r = (u + 0x7fffu + ((u >> 16) & 1u)) >> 16;
  return (unsigned short)r;
}
__device__ __forceinline__ float bf2f(unsigned short h) {
  return __uint_as_float((unsigned)h << 16);
}
__device__ __forceinline__ f32x4 mfma16(short8v a, short8v b, f32x4 c) {
  return __builtin_amdgcn_mfma_f32_16x16x32_bf16(a, b, c, 0, 0, 0);
}

// ---------------------------------------------------------------- sq of rows
template<int C>
__global__ __launch_bounds__(256) void sq_kernel(const float* __restrict__ xt,
                                                 float* __restrict__ sq) {
  int p = blockIdx.x * 256 + threadIdx.x;
  if (p >= BN) return;
  const float* r = xt + (size_t)p * C;
  float s = 0.f;
  if constexpr (C % 4 == 0) {
    for (int c4 = 0; c4 < C / 4; ++c4) { float4 v = *(const float4*)(r + c4 * 4); s += dot4(v, v); }
  } else {
    #pragma unroll
    for (int c = 0; c < C; ++c) { float v = r[c]; s += v * v; }
  }
  sq[p] = s;
}

// ------------------------------------------------- knn partial top-k per quadrant
template<int C, int MT>
__global__ __launch_bounds__(256) void knn_part(const float* __restrict__ xt,
    const float* __restrict__ sq, float* __restrict__ pval, int* __restrict__ pidx) {
  constexpr int MQ = Npts / NQ;
  __shared__ __align__(16) float chk[MT][C];
  __shared__ float csq[MT];
  const int t = threadIdx.x, w = t >> 6, l = t & 63;
  const int rowblk = blockIdx.x / NQ;
  const int q = blockIdx.x - rowblk * NQ;
  const int p0 = rowblk * 256;
  const int b = p0 / Npts;
  const int myrow = p0 + w * 64 + l;

  float cr[C];
  if constexpr (C >= 16) {
    __shared__ __align__(16) float stg[64][C + 4];
    for (int wv = 0; wv < 4; ++wv) {
      for (int e = t; e < 64 * C; e += 256) stg[e / C][e - (e / C) * C] =
          xt[((size_t)(p0 + wv * 64)) * C + e];
      __syncthreads();
      if (w == wv) {
        #pragma unroll
        for (int c4 = 0; c4 < C / 4; ++c4)
          *(float4*)(cr + c4 * 4) = *(const float4*)(&stg[l][c4 * 4]);
      }
      __syncthreads();
    }
  } else {
    #pragma unroll
    for (int c = 0; c < C; ++c) cr[c] = xt[(size_t)myrow * C + c];
  }
  const float sqn = sq[myrow];

  float vals[K_NN]; int ids[K_NN];
  #pragma unroll
  for (int i = 0; i < K_NN; ++i) { vals[i] = -FLT_MAX; ids[i] = 0; }

  const int mbase = q * MQ;
  for (int m0 = mbase; m0 < mbase + MQ; m0 += MT) {
    __syncthreads();
    const float* s2 = xt + ((size_t)b * Npts + m0) * C;
    for (int e = t; e < MT * C; e += 256) chk[e / C][e - (e / C) * C] = s2[e];
    for (int e = t; e < MT; e += 256) csq[e] = sq[b * Npts + m0 + e];
    __syncthreads();
    for (int j = 0; j < MT; ++j) {
      float dt = 0.f;
      if constexpr (C % 4 == 0) {
        #pragma unroll
        for (int c4 = 0; c4 < C / 4; ++c4)
          dt += dot4(*(const float4*)(cr + c4 * 4), *(const float4*)(&chk[j][c4 * 4]));
      } else {
        #pragma unroll
        for (int c = 0; c < C; ++c) dt += cr[c] * chk[j][c];
      }
      float nd = 2.f * dt - sqn - csq[j];
      if (nd > vals[K_NN - 1]) {          // strict: ties keep earlier (lower) index
        vals[K_NN - 1] = nd; ids[K_NN - 1] = m0 + j;
        #pragma unroll
        for (int i = K_NN - 1; i >= 1; --i) {
          if (vals[i] > vals[i - 1]) {
            float tv = vals[i]; vals[i] = vals[i-1]; vals[i-1] = tv;
            int ti = ids[i]; ids[i] = ids[i-1]; ids[i-1] = ti;
          }
        }
      }
    }
  }
  size_t base = ((size_t)q * BN + myrow) * K_NN;
  #pragma unroll
  for (int i = 0; i < K_NN; ++i) { pval[base + i] = vals[i]; pidx[base + i] = ids[i]; }
}

// ------------------------------------------------- merge NQ sorted lists -> top-20
__global__ __launch_bounds__(256) void knn_merge(const float* __restrict__ pval,
    const int* __restrict__ pidx, int* __restrict__ idxout) {
  int p = blockIdx.x * 256 + threadIdx.x;
  if (p >= BN) return;
  float vals[K_NN]; int ids[K_NN];
  size_t base = (size_t)p * K_NN;
  #pragma unroll
  for (int i = 0; i < K_NN; ++i) { vals[i] = pval[base + i]; ids[i] = pidx[base + i]; }
  for (int q = 1; q < NQ; ++q) {
    size_t b2 = ((size_t)q * BN + p) * K_NN;
    #pragma unroll
    for (int i = 0; i < K_NN; ++i) {
      float v = pval[b2 + i];
      if (v <= vals[K_NN - 1]) break;
      int m = pidx[b2 + i];
      vals[K_NN - 1] = v; ids[K_NN - 1] = m;
      #pragma unroll
      for (int r = K_NN - 1; r >= 1; --r) {
        if (vals[r] > vals[r - 1]) {
          float tv = vals[r]; vals[r] = vals[r-1]; vals[r-1] = tv;
          int ti = ids[r]; ids[r] = ids[r-1]; ids[r-1] = ti;
        }
      }
    }
  }
  int* op = idxout + (size_t)p * K_NN;
  #pragma unroll
  for (int i = 0; i < K_NN; ++i) op[i] = ids[i];
}

// ------------------------------------------------- prep: split weights to bf16 pairs
// W[O][2C] -> wlh/wll (W_lo hi/lo), dh/dl ((W_hi-W_lo) hi/lo), each [O][C]
template<int C, int O>
__global__ __launch_bounds__(256) void prep_w(const float* __restrict__ W,
    unsigned short* __restrict__ wlh, unsigned short* __restrict__ wll,
    unsigned short* __restrict__ dhh, unsigned short* __restrict__ dll) {
  int i = blockIdx.x * 256 + threadIdx.x;
  if (i >= O * C) return;
  int o = i / C, c = i - o * C;
  float wl = W[(size_t)o * 2 * C + c];
  float wh = W[(size_t)o * 2 * C + C + c];
  float d = wh - wl;
  unsigned short h1 = f2bf(wl);
  wlh[i] = h1; wll[i] = f2bf(wl - bf2f(h1));
  unsigned short h2 = f2bf(d);
  dhh[i] = h2; dll[i] = f2bf(d - bf2f(h2));
}

// ------------------------------------------------- MFMA edge conv (split-bf16, 3-term)
// P=4 points/block; rows 0..79 = neighbors (5 row-tiles, 20 quads = 5/point),
// rows 80..83 = center rows (ctr-tile vs D-weights), 84..95 zero pad.
// 4 waves split O into CTW=O/64 col-tiles of 16 each.
template<int C, int O>
__global__ __launch_bounds__(256, 2) void edge_mfma(const float* __restrict__ xt,
    const int* __restrict__ idx,
    const unsigned short* __restrict__ wlh, const unsigned short* __restrict__ wll,
    const unsigned short* __restrict__ dhh, const unsigned short* __restrict__ dll,
    float* __restrict__ mx, float* __restrict__ mn,
    float* __restrict__ psum, float* __restrict__ psq) {
  constexpr int P = 4, RTM = 5, RT = 6, NROW = 96;
  constexpr int KS = C / 32;
  constexpr int CTW = O / 64;
  constexpr int Cp = C + 8;                    // +16B pad: 2-way-max LDS banks
  __shared__ __align__(16) unsigned short Ah[NROW][Cp];
  __shared__ __align__(16) unsigned short Al[NROW][Cp];
  __shared__ float sbase[P][O];
  __shared__ int ids_s[NROW];
  const int t = threadIdx.x;
  const int p0 = blockIdx.x * P;

  if (t < NROW) {
    int id;
    if (t < P * K_NN) {
      int p = t / K_NN, k = t - p * K_NN;
      int b = p0 / Npts;
      id = b * Npts + idx[(size_t)(p0 + p) * K_NN + k];
    } else if (t < P * K_NN + P) id = p0 + (t - P * K_NN);
    else id = -1;
    ids_s[t] = id;
  }
  __syncthreads();
  for (int e = t; e < NROW * (C / 4); e += 256) {
    int row = e / (C / 4), c4 = e - row * (C / 4);
    int id = ids_s[row];
    float4 v = (id >= 0) ? *(const float4*)(xt + (size_t)id * C + c4 * 4)
                         : make_float4(0.f, 0.f, 0.f, 0.f);
    ushort4 h, lo;
    h.x = f2bf(v.x); lo.x = f2bf(v.x - bf2f(h.x));
    h.y = f2bf(v.y); lo.y = f2bf(v.y - bf2f(h.y));
    h.z = f2bf(v.z); lo.z = f2bf(v.z - bf2f(h.z));
    h.w = f2bf(v.w); lo.w = f2bf(v.w - bf2f(h.w));
    *(ushort4*)(&Ah[row][c4 * 4]) = h;
    *(ushort4*)(&Al[row][c4 * 4]) = lo;
  }
  __syncthreads();

  const int l = t & 63, wv = t >> 6;
  const int grp = l >> 4, l15 = l & 15;
  f32x4 acc[RT][CTW];
  #pragma unroll
  for (int rt = 0; rt < RT; ++rt)
    #pragma unroll
    for (int j = 0; j < CTW; ++j) acc[rt][j] = (f32x4){0.f, 0.f, 0.f, 0.f};

  for (int ks = 0; ks < KS; ++ks) {
    const int krd = ks * 32 + grp * 8;
    short8v ah[RT], al[RT];
    #pragma unroll
    for (int rt = 0; rt < RT; ++rt) {
      ah[rt] = *(const short8v*)(&Ah[rt * 16 + l15][krd]);
      al[rt] = *(const short8v*)(&Al[rt * 16 + l15][krd]);
    }
    #pragma unroll
    for (int j = 0; j < CTW; ++j) {
      const int col = (wv * CTW + j) * 16 + l15;
      const size_t boff = (size_t)col * C + krd;
      short8v bh = *(const short8v*)(wlh + boff);
      short8v bl = *(const short8v*)(wll + boff);
      #pragma unroll
      for (int rt = 0; rt < RTM; ++rt) {
        acc[rt][j] = mfma16(ah[rt], bh, acc[rt][j]);
        acc[rt][j] = mfma16(ah[rt], bl, acc[rt][j]);
        acc[rt][j] = mfma16(al[rt], bh, acc[rt][j]);
      }
      short8v ch = *(const short8v*)(dhh + boff);
      short8v cl = *(const short8v*)(dll + boff);
      acc[RTM][j] = mfma16(ah[RTM], ch, acc[RTM][j]);
      acc[RTM][j] = mfma16(ah[RTM], cl, acc[RTM][j]);
      acc[RTM][j] = mfma16(al[RTM], ch, acc[RTM][j]);
    }
  }

  // publish center term: ctr-tile rows 0..3 = points 0..3, held by grp0 regs
  if (grp == 0) {
    #pragma unroll
    for (int j = 0; j < CTW; ++j) {
      int col = (wv * CTW + j) * 16 + l15;
      #pragma unroll
      for (int r = 0; r < P; ++r) sbase[r][col] = acc[RTM][j][r];
    }
  }
  __syncthreads();

  // quad->point: row-tile rt (grp fixed) belongs to point p = rt - (rt > grp)
  #pragma unroll
  for (int j = 0; j < CTW; ++j) {
    const int col = (wv * CTW + j) * 16 + l15;
    float bp0 = sbase[0][col], bp1 = sbase[1][col];
    float bp2 = sbase[2][col], bp3 = sbase[3][col];
    float bsel[RTM];
    bsel[0] = bp0;
    bsel[1] = (1 <= grp) ? bp1 : bp0;
    bsel[2] = (2 <= grp) ? bp2 : bp1;
    bsel[3] = (3 <= grp) ? bp3 : bp2;
    bsel[4] = bp3;
    float pmx[RTM], pmn[RTM];
    float lsum = 0.f, lsq = 0.f;
    #pragma unroll
    for (int rt = 0; rt < RTM; ++rt) {
      float y0 = acc[rt][j][0] + bsel[rt];
      float y1 = acc[rt][j][1] + bsel[rt];
      float y2 = acc[rt][j][2] + bsel[rt];
      float y3 = acc[rt][j][3] + bsel[rt];
      lsum += (y0 + y1) + (y2 + y3);
      lsq = fmaf(y0, y0, lsq); lsq = fmaf(y1, y1, lsq);
      lsq = fmaf(y2, y2, lsq); lsq = fmaf(y3, y3, lsq);
      pmx[rt] = fmaxf(fmaxf(y0, y1), fmaxf(y2, y3));
      pmn[rt] = fminf(fminf(y0, y1), fminf(y2, y3));
    }
    #pragma unroll
    for (int p = 0; p < P; ++p) {
      float xm = (p <= grp) ? pmx[p] : pmx[p + 1];
      float fm = (p == grp) ? fmaxf(xm, pmx[p + 1]) : xm;
      float xn = (p <= grp) ? pmn[p] : pmn[p + 1];
      float fn = (p == grp) ? fminf(xn, pmn[p + 1]) : xn;
      fm = fmaxf(fm, __shfl_xor(fm, 16)); fm = fmaxf(fm, __shfl_xor(fm, 32));
      fn = fminf(fn, __shfl_xor(fn, 16)); fn = fminf(fn, __shfl_xor(fn, 32));
      if (grp == 0) {
        size_t ob = (size_t)(p0 + p) * O + col;
        mx[ob] = fm; mn[ob] = fn;
      }
    }
    lsum += __shfl_xor(lsum, 16); lsum += __shfl_xor(lsum, 32);
    lsq  += __shfl_xor(lsq , 16); lsq  += __shfl_xor(lsq , 32);
    if (grp == 0) {
      psum[(size_t)blockIdx.x * O + col] = lsum;
      psq [(size_t)blockIdx.x * O + col] = lsq;
    }
  }
}

// ------------------------------------------------- vector edge conv (layer 1, C=3)
template<int C, int O, int G, int NPG, int CPT>
__global__ __launch_bounds__(256) void edge_kernel(const float* __restrict__ xt,
    const int* __restrict__ idx, const float* __restrict__ W,
    float* __restrict__ mx, float* __restrict__ mn,
    float* __restrict__ psum, float* __restrict__ psq) {
  constexpr int WP = O / (64 * CPT);
  constexpr int TPB = 64 * WP * NPG;
  constexpr int PPG = G / NPG;
  static_assert(TPB == 256, "block must be 256 threads");
  __shared__ __align__(16) float pts[G][K_NN + 1][C];
  __shared__ int ids[G][K_NN + 1];
  __shared__ float shps[NPG][O];
  __shared__ float shpq[NPG][O];
  const int t = threadIdx.x;
  const int p0 = blockIdx.x * G;
  const int b = p0 / Npts;

  for (int e = t; e < G * (K_NN + 1); e += TPB) {
    int g = e / (K_NN + 1), j = e - g * (K_NN + 1);
    ids[g][j] = (j == 0) ? (p0 + g) : (b * Npts + idx[(size_t)(p0 + g) * K_NN + (j - 1)]);
  }
  __syncthreads();
  for (int e = t; e < G * (K_NN + 1) * C; e += TPB) {
    int g = e / ((K_NN + 1) * C), rem = e - g * ((K_NN + 1) * C);
    int j = rem / C, c = rem - j * C;
    pts[g][j][c] = xt[(size_t)ids[g][j] * C + c];
  }
  __syncthreads();

  const int w = t >> 6, l = t & 63;
  const int pg = w / WP, wp = w - pg * WP;
  const int o0 = wp * 64 + l;
  float ls0 = 0.f, lq0 = 0.f;

  for (int it = 0; it < PPG; ++it) {
    const int g = pg * PPG + it;
    float yk0[K_NN];
    float u0 = 0.f, v0 = 0.f;
    #pragma unroll
    for (int k = 0; k < K_NN; ++k) yk0[k] = 0.f;
    const float* W0 = W + (size_t)o0 * (2 * C);
    #pragma unroll
    for (int c = 0; c < C; ++c) {
      const float wl = W0[c], wh = W0[C + c], ccv = pts[g][0][c];
      u0 += wl * ccv; v0 += wh * ccv;
      #pragma unroll
      for (int k = 0; k < K_NN; ++k) yk0[k] += wl * pts[g][k + 1][c];
    }
    const int n = p0 + g - b * Npts;
    const size_t obase = ((size_t)b * Npts + n) * O;
    const float base = v0 - u0;
    float vmx = -FLT_MAX, vmn = FLT_MAX;
    #pragma unroll
    for (int k = 0; k < K_NN; ++k) {
      float y = yk0[k] + base;
      ls0 += y; lq0 += y * y;
      vmx = fmaxf(vmx, y); vmn = fminf(vmn, y);
    }
    mx[obase + o0] = vmx; mn[obase + o0] = vmn;
  }

  shps[pg][o0] = ls0; shpq[pg][o0] = lq0;
  __syncthreads();
  if (t < O) {
    float s = 0.f, qq = 0.f;
    #pragma unroll
    for (int i = 0; i < NPG; ++i) { s += shps[i][t]; qq += shpq[i][t]; }
    psum[(size_t)blockIdx.x * O + t] = s;
    psq [(size_t)blockIdx.x * O + t] = qq;
  }
}

// ------------------------------------------------- finalize BN stats per channel
template<int O>
__global__ __launch_bounds__(256) void stats_kernel(const float* __restrict__ psum,
    const float* __restrict__ psq, int nblk,
    const float* __restrict__ gamma, const float* __restrict__ beta,
    float* __restrict__ scale, float* __restrict__ bias) {
  const int l = threadIdx.x & 63, w = threadIdx.x >> 6;
  const int o = blockIdx.x * 64 + l;
  double s = 0.0, ss = 0.0;
  for (int i = w; i < nblk; i += 4) {
    s  += (double)psum[(size_t)i * O + o];
    ss += (double)psq [(size_t)i * O + o];
  }
  __shared__ double sh[2][4][64];
  sh[0][w][l] = s; sh[1][w][l] = ss;
  __syncthreads();
  if (w == 0) {
    s  = sh[0][0][l] + sh[0][1][l] + sh[0][2][l] + sh[0][3][l];
    ss = sh[1][0][l] + sh[1][1][l] + sh[1][2][l] + sh[1][3][l];
    double cnt = (double)Bsz * Npts * K_NN;
    double m = s / cnt;
    double var = ss / cnt - m * m;
    float g = gamma[o];
    float sc = g * rsqrtf((float)var + EPS);
    scale[o] = sc;
    bias[o] = beta[o] - (float)m * sc;
  }
}

// ------------------------------------------------- reset pooled accumulators
__global__ __launch_bounds__(256) void reset_pool(unsigned* __restrict__ pooled) {
  int i = blockIdx.x * 256 + threadIdx.x;
  if (i < Bsz * 448) pooled[i] = 0u;   // 0 < encf(f) for all finite f
}

// ------------------------------------------------- normalize + lrelu + fused max-pool
template<int O, int COFF, bool WNC>
__global__ __launch_bounds__(256) void apply_kernel(const float* __restrict__ mx,
    const float* __restrict__ mn, const float* __restrict__ scale,
    const float* __restrict__ bias, float* __restrict__ xnc,
    unsigned* __restrict__ pooled) {
  constexpr int OT = O / 64;
  constexpr int NCH = Npts / 256;
  const int bid = blockIdx.x;
  const int nchunk = bid % NCH;
  const int ot = (bid / NCH) % OT;
  const int b = bid / (NCH * OT);
  const int l = threadIdx.x & 63, w = threadIdx.x >> 6;
  const int o = ot * 64 + l;
  const float sc = scale[o], bs = bias[o];
  const bool pos = (sc >= 0.f);
  float vmax = -FLT_MAX;
  const int n0 = nchunk * 256;
  for (int i = 0; i < 64; ++i) {
    int n = n0 + w + i * 4;
    size_t ix = ((size_t)b * Npts + n) * O + o;
    float raw = pos ? mx[ix] : mn[ix];   // max for +scale, min for -scale
    float y = raw * sc + bs;
    y = (y >= 0.f) ? y : SLOPE * y;
    if constexpr (WNC) xnc[ix] = y;
    vmax = fmaxf(vmax, y);
  }
  __shared__ float sh[4][64];
  sh[w][l] = vmax;
  __syncthreads();
  if (w == 0) {
    float m = fmaxf(fmaxf(sh[0][l], sh[1][l]), fmaxf(sh[2][l], sh[3][l]));
    atomicMax(pooled + b * 448 + COFF + o, encf(m));
  }
}

// ------------------------------------------------- FC layers
template<int CIN, bool LRELU, bool DECODE>
__global__ __launch_bounds__(64) void fc_kernel(const void* __restrict__ inv,
    const float* __restrict__ Wt, float* __restrict__ out, int JO) {
  int j = blockIdx.x;
  const float* wr = Wt + (size_t)j * CIN;
  float acc[Bsz];
  #pragma unroll
  for (int b = 0; b < Bsz; ++b) acc[b] = 0.f;
  for (int c = threadIdx.x; c < CIN; c += 64) {
    float wv = wr[c];
    #pragma unroll
    for (int b = 0; b < Bsz; ++b) {
      float x;
      if constexpr (DECODE) x = decf(((const unsigned*)inv)[b * CIN + c]);
      else                  x = ((const float*)inv)[b * CIN + c];
      acc[b] += x * wv;
    }
  }
  #pragma unroll
  for (int b = 0; b < Bsz; ++b) {
    float v = acc[b];
    #pragma unroll
    for (int w = 32; w > 0; w >>= 1) v += __shfl_down(v, w);
    if (threadIdx.x == 0) {
      if (LRELU) v = (v >= 0.f) ? v : SLOPE * v;
      out[b * JO + j] = v;
    }
  }
}

// ================================================================ launch
extern "C" void kernel_launch(void* const* d_in, const int* in_sizes, int n_in,
                              void* d_out, int out_size, void* d_ws, size_t ws_size,
                              hipStream_t stream) {
  const float* x   = (const float*)d_in[0];
  const float* W1  = (const float*)d_in[1];
  const float* g1  = (const float*)d_in[2];
  const float* b1  = (const float*)d_in[3];
  const float* W2  = (const float*)d_in[4];
  const float* g2  = (const float*)d_in[5];
  const float* b2  = (const float*)d_in[6];
  const float* W3  = (const float*)d_in[7];
  const float* g3  = (const float*)d_in[8];
  const float* b3  = (const float*)d_in[9];
  const float* L1  = (const float*)d_in[10];
  const float* L2  = (const float*)d_in[11];
  float* out = (float*)d_out;

  float* ws = (float*)d_ws;
  size_t off = 0;
  float* sq    = ws + off; off += BN;
  int*   idxb  = (int*)(ws + off); off += (size_t)BN * K_NN;
  float* mx    = ws + off; off += (size_t)BN * 256;
  float* mn    = ws + off; off += (size_t)BN * 256;
  float* psum  = ws + off; off += (size_t)4096 * 256;
  float* psq   = ws + off; off += (size_t)4096 * 256;
  float* scale = ws + off; off += 256;
  float* bias  = ws + off; off += 256;
  float* x1nc  = ws + off; off += (size_t)BN * 64;
  float* x2nc  = ws + off; off += (size_t)BN * 128;
  unsigned* pooled = (unsigned*)(ws + off); off += Bsz * 448;
  float* h     = ws + off; off += Bsz * 1024;
  unsigned short* wlh2 = (unsigned short*)(ws + off); off += 128 * 64 / 2;
  unsigned short* wll2 = (unsigned short*)(ws + off); off += 128 * 64 / 2;
  unsigned short* dh2  = (unsigned short*)(ws + off); off += 128 * 64 / 2;
  unsigned short* dl2  = (unsigned short*)(ws + off); off += 128 * 64 / 2;
  unsigned short* wlh3 = (unsigned short*)(ws + off); off += 256 * 128 / 2;
  unsigned short* wll3 = (unsigned short*)(ws + off); off += 256 * 128 / 2;
  unsigned short* dh3  = (unsigned short*)(ws + off); off += 256 * 128 / 2;
  unsigned short* dl3  = (unsigned short*)(ws + off); off += 256 * 128 / 2;
  // knn partial lists overlay mx/mn (disjoint lifetimes)
  float* pval = mx;
  int*   pidx = (int*)mn;

  reset_pool<<<14, 256, 0, stream>>>(pooled);
  prep_w<64, 128><<<(128 * 64 + 255) / 256, 256, 0, stream>>>(W2, wlh2, wll2, dh2, dl2);
  prep_w<128, 256><<<(256 * 128 + 255) / 256, 256, 0, stream>>>(W3, wlh3, wll3, dh3, dl3);

  // ---- edge block 1: C=3 -> O=64 (fp32 vector)
  sq_kernel<3><<<64, 256, 0, stream>>>(x, sq);
  knn_part<3, 64><<<(BN / 256) * NQ, 256, 0, stream>>>(x, sq, pval, pidx);
  knn_merge<<<64, 256, 0, stream>>>(pval, pidx, idxb);
  edge_kernel<3, 64, 16, 4, 1><<<BN / 16, 256, 0, stream>>>(x, idxb, W1, mx, mn, psum, psq);
  stats_kernel<64><<<1, 256, 0, stream>>>(psum, psq, BN / 16, g1, b1, scale, bias);
  apply_kernel<64, 0, true><<<8 * 1 * 8, 256, 0, stream>>>(mx, mn, scale, bias, x1nc, pooled);

  // ---- edge block 2: C=64 -> O=128 (MFMA split-bf16)
  sq_kernel<64><<<64, 256, 0, stream>>>(x1nc, sq);
  knn_part<64, 64><<<(BN / 256) * NQ, 256, 0, stream>>>(x1nc, sq, pval, pidx);
  knn_merge<<<64, 256, 0, stream>>>(pval, pidx, idxb);
  edge_mfma<64, 128><<<BN / 4, 256, 0, stream>>>(x1nc, idxb, wlh2, wll2, dh2, dl2,
                                                 mx, mn, psum, psq);
  stats_kernel<128><<<2, 256, 0, stream>>>(psum, psq, BN / 4, g2, b2, scale, bias);
  apply_kernel<128, 64, true><<<8 * 2 * 8, 256, 0, stream>>>(mx, mn, scale, bias, x2nc, pooled);

  // ---- edge block 3: C=128 -> O=256 (MFMA split-bf16)
  sq_kernel<128><<<64, 256, 0, stream>>>(x2nc, sq);
  knn_part<128, 32><<<(BN / 256) * NQ, 256, 0, stream>>>(x2nc, sq, pval, pidx);
  knn_merge<<<64, 256, 0, stream>>>(pval, pidx, idxb);
  edge_mfma<128, 256><<<BN / 4, 256, 0, stream>>>(x2nc, idxb, wlh3, wll3, dh3, dl3,
                                                  mx, mn, psum, psq);
  stats_kernel<256><<<4, 256, 0, stream>>>(psum, psq, BN / 4, g3, b3, scale, bias);
  apply_kernel<256, 192, false><<<8 * 4 * 8, 256, 0, stream>>>(mx, mn, scale, bias, nullptr, pooled);

  // ---- head
  fc_kernel<448, true, true><<<1024, 64, 0, stream>>>(pooled, L1, h, 1024);
  fc_kernel<1024, false, false><<<2500, 64, 0, stream>>>(h, L2, out, 2500);
}